// Round 2
// baseline (599.101 us; speedup 1.0000x reference)
//
#include <hip/hip_runtime.h>

typedef unsigned short u16;
typedef __attribute__((ext_vector_type(8))) short short8;
typedef __attribute__((ext_vector_type(4))) float f32x4;

#define D_DIM   1024
#define N3      3072
#define ROWS    32768   // B*T = 4*8192
#define T_DIM   8192
#define BM      64
#define BK      64
#define LDK     (BK + 8)   // +8 bf16 pad -> row stride 144B -> only 2-way bank aliasing (free)

__device__ __forceinline__ float bf2f(u16 u) {
    union { unsigned int i; float f; } c; c.i = ((unsigned int)u) << 16; return c.f;
}
__device__ __forceinline__ u16 f2bf(float f) {
    union { float f; unsigned int i; } c; c.f = f;
    unsigned int r = c.i + 0x7FFF + ((c.i >> 16) & 1);   // RNE
    return (u16)(r >> 16);
}

// ---------------- Kernel 1: convert+transpose Wqkv (1024 x 3072 fp32) -> WT (3072 x 1024 bf16) ----
__global__ void transpose_w(const float* __restrict__ W, u16* __restrict__ WT) {
    __shared__ u16 tile[32][34];
    int nb = blockIdx.x * 32;   // n base
    int kb = blockIdx.y * 32;   // k base
    int tx = threadIdx.x;       // 0..31
    int ty = threadIdx.y;       // 0..7
    #pragma unroll
    for (int i = 0; i < 32; i += 8)
        tile[ty + i][tx] = f2bf(W[(size_t)(kb + ty + i) * N3 + nb + tx]);
    __syncthreads();
    #pragma unroll
    for (int i = 0; i < 32; i += 8)
        WT[(size_t)(nb + ty + i) * D_DIM + kb + tx] = tile[tx][ty + i];
}

// ---------------- Kernel 2: fused GEMM (q,k,v chunks together) + row sumsq + P=k*v ----------------
__global__ __launch_bounds__(256, 2)
void gemm_fused(const float* __restrict__ x, const u16* __restrict__ WT,
                const float* __restrict__ bqkv,
                u16* __restrict__ qb,            // raw q, bf16
                u16* __restrict__ P,             // k*v, bf16
                float* __restrict__ qinv, float* __restrict__ kinv)
{
    __shared__ __align__(16) u16 a_sh[BM * LDK];
    __shared__ __align__(16) u16 b_sh[3][128 * LDK];
    __shared__ float rss_q[BM], rss_k[BM];

    const int tid  = threadIdx.x;
    const int lane = tid & 63;
    const int w    = tid >> 6;     // wave 0..3
    const int l15  = lane & 15;
    const int quad = lane >> 4;    // 0..3
    const int r0   = blockIdx.x * BM;

    if (tid < BM) { rss_q[tid] = 0.0f; rss_k[tid] = 0.0f; }
    // ordering vs first atomicAdd is covered by the syncthreads inside the k-loop

    for (int j = 0; j < 8; ++j) {
        const int jb = j * 128;
        f32x4 acc[3][4][2];
        #pragma unroll
        for (int t = 0; t < 3; ++t)
            #pragma unroll
            for (int mt = 0; mt < 4; ++mt)
                #pragma unroll
                for (int nt = 0; nt < 2; ++nt) acc[t][mt][nt] = (f32x4)(0.0f);

        for (int k0 = 0; k0 < D_DIM; k0 += BK) {
            __syncthreads();   // protect LDS from previous iteration's readers
            // stage A tile: 64 rows x 64 k, fp32 -> bf16 in flight
            #pragma unroll
            for (int i = 0; i < 2; ++i) {
                int V = tid + 256 * i;
                int r = V >> 3, c = (V & 7) * 8;
                const float* s = x + (size_t)(r0 + r) * D_DIM + k0 + c;
                float4 f0 = *reinterpret_cast<const float4*>(s);
                float4 f1 = *reinterpret_cast<const float4*>(s + 4);
                short8 v;
                v[0] = (short)f2bf(f0.x); v[1] = (short)f2bf(f0.y);
                v[2] = (short)f2bf(f0.z); v[3] = (short)f2bf(f0.w);
                v[4] = (short)f2bf(f1.x); v[5] = (short)f2bf(f1.y);
                v[6] = (short)f2bf(f1.z); v[7] = (short)f2bf(f1.w);
                *reinterpret_cast<short8*>(&a_sh[r * LDK + c]) = v;
            }
            // stage 3 B tiles (q,k,v chunks at same j): each 128 n-rows x 64 k, bf16
            #pragma unroll
            for (int t = 0; t < 3; ++t)
                #pragma unroll
                for (int i = 0; i < 4; ++i) {
                    int V = tid + 256 * i;
                    int n = V >> 3, c = (V & 7) * 8;
                    short8 v = *reinterpret_cast<const short8*>(
                        WT + (size_t)(t * 1024 + jb + n) * D_DIM + k0 + c);
                    *reinterpret_cast<short8*>(&b_sh[t][n * LDK + c]) = v;
                }
            __syncthreads();
            #pragma unroll
            for (int ks = 0; ks < 2; ++ks) {
                short8 aF[4];
                #pragma unroll
                for (int mt = 0; mt < 4; ++mt)
                    aF[mt] = *reinterpret_cast<const short8*>(
                        &a_sh[(mt * 16 + l15) * LDK + ks * 32 + quad * 8]);
                #pragma unroll
                for (int t = 0; t < 3; ++t)
                    #pragma unroll
                    for (int nt = 0; nt < 2; ++nt) {
                        short8 bF = *reinterpret_cast<const short8*>(
                            &b_sh[t][(w * 32 + nt * 16 + l15) * LDK + ks * 32 + quad * 8]);
                        #pragma unroll
                        for (int mt = 0; mt < 4; ++mt)
                            acc[t][mt][nt] = __builtin_amdgcn_mfma_f32_16x16x32_bf16(
                                aF[mt], bF, acc[t][mt][nt], 0, 0, 0);
                    }
            }
        }

        // add bqkv bias (fp32, column-indexed)
        #pragma unroll
        for (int t = 0; t < 3; ++t)
            #pragma unroll
            for (int nt = 0; nt < 2; ++nt) {
                float bq = bqkv[t * 1024 + jb + w * 32 + nt * 16 + l15];
                #pragma unroll
                for (int mt = 0; mt < 4; ++mt)
                    #pragma unroll
                    for (int rg = 0; rg < 4; ++rg) acc[t][mt][nt][rg] += bq;
            }

        // accumulate row sum-of-squares for q (t=0) and k (t=1)
        #pragma unroll
        for (int t = 0; t < 2; ++t)
            #pragma unroll
            for (int mt = 0; mt < 4; ++mt)
                #pragma unroll
                for (int rg = 0; rg < 4; ++rg) {
                    float s = acc[t][mt][0][rg] * acc[t][mt][0][rg]
                            + acc[t][mt][1][rg] * acc[t][mt][1][rg];
                    #pragma unroll
                    for (int m = 1; m < 16; m <<= 1) s += __shfl_xor(s, m, 16);
                    if (l15 == 0)
                        atomicAdd(t == 0 ? &rss_q[mt * 16 + quad * 4 + rg]
                                         : &rss_k[mt * 16 + quad * 4 + rg], s);
                }

        // store q (raw bf16) and P = k*v (bf16)
        #pragma unroll
        for (int mt = 0; mt < 4; ++mt)
            #pragma unroll
            for (int nt = 0; nt < 2; ++nt) {
                int col = jb + w * 32 + nt * 16 + l15;
                #pragma unroll
                for (int rg = 0; rg < 4; ++rg) {
                    int row = r0 + mt * 16 + quad * 4 + rg;
                    size_t o = (size_t)row * D_DIM + col;
                    qb[o] = f2bf(acc[0][mt][nt][rg]);
                    P[o]  = f2bf(acc[1][mt][nt][rg] * acc[2][mt][nt][rg]);
                }
            }
    }
    __syncthreads();
    if (tid < BM) {
        qinv[r0 + tid] = rsqrtf(rss_q[tid]);
        kinv[r0 + tid] = rsqrtf(rss_k[tid]);
    }
}

// ---------------- Kernel 3: kv[b,d] = sum_t P[b,t,d] * kinv[b,t] ----------------
__global__ void kv_reduce(const u16* __restrict__ P, const float* __restrict__ kinv,
                          float* __restrict__ kv)
{
    int d  = blockIdx.x * 256 + threadIdx.x;   // grid.x = 4 -> d in [0,1024)
    int b  = blockIdx.z;                       // grid.z = 4
    int t0 = blockIdx.y * 256;                 // grid.y = 32
    int rowbase = b * T_DIM + t0;
    float s0 = 0.f, s1 = 0.f, s2 = 0.f, s3 = 0.f;
    for (int tt = 0; tt < 256; tt += 4) {
        int r = rowbase + tt;
        s0 += bf2f(P[(size_t)(r + 0) * D_DIM + d]) * kinv[r + 0];
        s1 += bf2f(P[(size_t)(r + 1) * D_DIM + d]) * kinv[r + 1];
        s2 += bf2f(P[(size_t)(r + 2) * D_DIM + d]) * kinv[r + 2];
        s3 += bf2f(P[(size_t)(r + 3) * D_DIM + d]) * kinv[r + 3];
    }
    atomicAdd(&kv[b * D_DIM + d], (s0 + s1) + (s2 + s3));
}

// ---------------- Kernel 4: out = q*qinv*kv*scale + bias (fp32 out) ----------------
__global__ void finalize(const u16* __restrict__ qb, const float* __restrict__ qinv,
                         const float* __restrict__ kv, const float* __restrict__ scale,
                         const float* __restrict__ bias, float* __restrict__ out)
{
    size_t idx = (size_t)blockIdx.x * 256 + threadIdx.x;   // vec8 index
    int row = (int)(idx >> 7);
    int dv  = ((int)idx & 127) * 8;
    int b   = row >> 13;
    float qi = qinv[row];
    short8 qv = *reinterpret_cast<const short8*>(qb + (size_t)row * D_DIM + dv);
    const float* kvp = kv + b * D_DIM + dv;
    const float* sp  = scale + dv;
    const float* bp  = bias + dv;
    float4 o0, o1;
    o0.x = bf2f((u16)qv[0]) * qi * kvp[0] * sp[0] + bp[0];
    o0.y = bf2f((u16)qv[1]) * qi * kvp[1] * sp[1] + bp[1];
    o0.z = bf2f((u16)qv[2]) * qi * kvp[2] * sp[2] + bp[2];
    o0.w = bf2f((u16)qv[3]) * qi * kvp[3] * sp[3] + bp[3];
    o1.x = bf2f((u16)qv[4]) * qi * kvp[4] * sp[4] + bp[4];
    o1.y = bf2f((u16)qv[5]) * qi * kvp[5] * sp[5] + bp[5];
    o1.z = bf2f((u16)qv[6]) * qi * kvp[6] * sp[6] + bp[6];
    o1.w = bf2f((u16)qv[7]) * qi * kvp[7] * sp[7] + bp[7];
    float* op = out + (size_t)row * D_DIM + dv;
    *reinterpret_cast<float4*>(op)     = o0;
    *reinterpret_cast<float4*>(op + 4) = o1;
}

extern "C" void kernel_launch(void* const* d_in, const int* in_sizes, int n_in,
                              void* d_out, int out_size, void* d_ws, size_t ws_size,
                              hipStream_t stream) {
    const float* x     = (const float*)d_in[0];
    const float* W     = (const float*)d_in[1];
    const float* bqkv  = (const float*)d_in[2];
    const float* scale = (const float*)d_in[3];
    const float* bias  = (const float*)d_in[4];
    float* out = (float*)d_out;

    char* ws = (char*)d_ws;
    u16*   WT   = (u16*)ws;                        // 6,291,456 B
    u16*   qb   = (u16*)(ws + 6291456);            // 67,108,864 B
    u16*   P    = (u16*)(ws + 73400320);           // 67,108,864 B
    float* qinv = (float*)(ws + 140509184);        // 131,072 B
    float* kinv = (float*)(ws + 140640256);        // 131,072 B
    float* kv   = (float*)(ws + 140771328);        // 16,384 B

    transpose_w<<<dim3(96, 32), dim3(32, 8), 0, stream>>>(W, WT);
    gemm_fused<<<dim3(ROWS / BM), dim3(256), 0, stream>>>(x, WT, bqkv, qb, P, qinv, kinv);
    hipMemsetAsync(kv, 0, 4 * D_DIM * sizeof(float), stream);
    kv_reduce<<<dim3(4, 32, 4), dim3(256), 0, stream>>>(P, kinv, kv);
    finalize<<<dim3((ROWS * (D_DIM / 8)) / 256), dim3(256), 0, stream>>>(qb, qinv, kv, scale, bias, out);
}

// Round 3
// 591.069 us; speedup vs baseline: 1.0136x; 1.0136x over previous
//
#include <hip/hip_runtime.h>

typedef unsigned short u16;
typedef __attribute__((ext_vector_type(8))) short short8;
typedef __attribute__((ext_vector_type(4))) float f32x4;

#define D_DIM   1024
#define ROWS    32768   // B*T = 4*8192
#define T_DIM   8192

__device__ __forceinline__ float bf2f(u16 u) {
    union { unsigned int i; float f; } c; c.i = ((unsigned int)u) << 16; return c.f;
}
__device__ __forceinline__ u16 f2bf(float f) {
    union { float f; unsigned int i; } c; c.f = f;
    unsigned int r = c.i + 0x7FFF + ((c.i >> 16) & 1);   // RNE
    return (u16)(r >> 16);
}

#define GLL16(gp, lp) \
    __builtin_amdgcn_global_load_lds((const __attribute__((address_space(1))) void*)(gp), \
                                     (__attribute__((address_space(3))) void*)(lp), 16, 0, 0)

// ---------------- Kernel 0: x fp32 -> xb bf16 ----------------
__global__ void convert_x(const float* __restrict__ x, u16* __restrict__ xb) {
    size_t idx = ((size_t)blockIdx.x * 256 + threadIdx.x) * 8;
    float4 f0 = *reinterpret_cast<const float4*>(x + idx);
    float4 f1 = *reinterpret_cast<const float4*>(x + idx + 4);
    short8 v;
    v[0] = (short)f2bf(f0.x); v[1] = (short)f2bf(f0.y);
    v[2] = (short)f2bf(f0.z); v[3] = (short)f2bf(f0.w);
    v[4] = (short)f2bf(f1.x); v[5] = (short)f2bf(f1.y);
    v[6] = (short)f2bf(f1.z); v[7] = (short)f2bf(f1.w);
    *reinterpret_cast<short8*>(xb + idx) = v;
}

// ---------------- Kernel 1: convert+transpose Wqkv (1024x3072 fp32) -> WT (3072x1024 bf16) ----
__global__ void transpose_w(const float* __restrict__ W, u16* __restrict__ WT) {
    __shared__ u16 tile[32][34];
    int nb = blockIdx.x * 32;
    int kb = blockIdx.y * 32;
    int tx = threadIdx.x;   // 0..31
    int ty = threadIdx.y;   // 0..7
    #pragma unroll
    for (int i = 0; i < 32; i += 8)
        tile[ty + i][tx] = f2bf(W[(size_t)(kb + ty + i) * 3072 + nb + tx]);
    __syncthreads();
    #pragma unroll
    for (int i = 0; i < 32; i += 8)
        WT[(size_t)(nb + ty + i) * D_DIM + kb + tx] = tile[tx][ty + i];
}

// ---------------- Kernel 2: m97-style GEMM, 128x128 tile, GLL staging, XOR-swizzled LDS ----
// C[row, col] = sum_k xb[row,k] * WT[col,k] + bqkv[col]
// by<8: q cols -> qb + row-sumsq -> qssq ; by 8..15: k -> kvb + kssq ; by>=16: v -> kvb
__global__ __launch_bounds__(256)
void gemm_k(const u16* __restrict__ xb, const u16* __restrict__ WT,
            const float* __restrict__ bqkv,
            u16* __restrict__ qb, u16* __restrict__ kvb,
            float* __restrict__ qssq, float* __restrict__ kssq)
{
    // LDS tiles: 128 rows x 64 k bf16, 16B-group swizzle: slot(row,g) = row*8 + (g ^ (row&7))
    __shared__ __align__(16) u16 a_sh[128 * 64];
    __shared__ __align__(16) u16 b_sh[128 * 64];

    const int tid  = threadIdx.x;
    const int lane = tid & 63;
    const int w    = tid >> 6;      // wave 0..3
    const int l15  = lane & 15;
    const int quad = lane >> 4;     // 0..3
    const int wm   = w & 1;         // wave quadrant
    const int wn   = w >> 1;
    const int r0   = blockIdx.x * 128;
    const int by   = blockIdx.y;    // 0..23
    const int c0   = by * 128;

    // staging source pointers (per-lane, swizzled), 4 GLL per wave per tile
    const u16* aptr[4];
    const u16* bptr[4];
    u16* alds[4];
    u16* blds[4];
    #pragma unroll
    for (int i = 0; i < 4; ++i) {
        int s    = w * 256 + i * 64 + lane;     // 16B-slot index
        int row  = s >> 3;
        int gsrc = (s & 7) ^ (row & 7);
        aptr[i] = xb + (size_t)(r0 + row) * D_DIM + gsrc * 8;
        bptr[i] = WT + (size_t)(c0 + row) * D_DIM + gsrc * 8;
        alds[i] = &a_sh[(w * 256 + i * 64) * 8];   // wave-uniform base
        blds[i] = &b_sh[(w * 256 + i * 64) * 8];
    }

    // fragment read bases (row&7 == l15&7 for all mt/nt since tile row offsets are mult of 8)
    const int g0 = quad ^ (l15 & 7);
    const int g1 = (quad + 4) ^ (l15 & 7);
    const u16* aRd0 = &a_sh[(wm * 64 + l15) * 64 + g0 * 8];
    const u16* aRd1 = &a_sh[(wm * 64 + l15) * 64 + g1 * 8];
    const u16* bRd0 = &b_sh[(wn * 64 + l15) * 64 + g0 * 8];
    const u16* bRd1 = &b_sh[(wn * 64 + l15) * 64 + g1 * 8];

    f32x4 acc[4][4];
    #pragma unroll
    for (int mt = 0; mt < 4; ++mt)
        #pragma unroll
        for (int nt = 0; nt < 4; ++nt) acc[mt][nt] = (f32x4)(0.0f);

    for (int kk = 0; kk < 16; ++kk) {
        __syncthreads();   // previous iteration's readers done
        #pragma unroll
        for (int i = 0; i < 4; ++i) {
            GLL16(aptr[i], alds[i]);
            GLL16(bptr[i], blds[i]);
            aptr[i] += 64;
            bptr[i] += 64;
        }
        __syncthreads();   // staging complete (vmcnt drained by barrier)

        short8 aF[4], bF[4];
        // ks = 0 (k 0..31 of this 64-block)
        #pragma unroll
        for (int mt = 0; mt < 4; ++mt)
            aF[mt] = *reinterpret_cast<const short8*>(aRd0 + mt * 1024);
        #pragma unroll
        for (int nt = 0; nt < 4; ++nt)
            bF[nt] = *reinterpret_cast<const short8*>(bRd0 + nt * 1024);
        #pragma unroll
        for (int mt = 0; mt < 4; ++mt)
            #pragma unroll
            for (int nt = 0; nt < 4; ++nt)
                acc[mt][nt] = __builtin_amdgcn_mfma_f32_16x16x32_bf16(
                    aF[mt], bF[nt], acc[mt][nt], 0, 0, 0);
        // ks = 1 (k 32..63)
        #pragma unroll
        for (int mt = 0; mt < 4; ++mt)
            aF[mt] = *reinterpret_cast<const short8*>(aRd1 + mt * 1024);
        #pragma unroll
        for (int nt = 0; nt < 4; ++nt)
            bF[nt] = *reinterpret_cast<const short8*>(bRd1 + nt * 1024);
        #pragma unroll
        for (int mt = 0; mt < 4; ++mt)
            #pragma unroll
            for (int nt = 0; nt < 4; ++nt)
                acc[mt][nt] = __builtin_amdgcn_mfma_f32_16x16x32_bf16(
                    aF[mt], bF[nt], acc[mt][nt], 0, 0, 0);
    }

    // ---- epilogue: bias ----
    float bcol[4];
    #pragma unroll
    for (int nt = 0; nt < 4; ++nt)
        bcol[nt] = bqkv[c0 + wn * 64 + nt * 16 + l15];
    #pragma unroll
    for (int mt = 0; mt < 4; ++mt)
        #pragma unroll
        for (int nt = 0; nt < 4; ++nt)
            #pragma unroll
            for (int rg = 0; rg < 4; ++rg) acc[mt][nt][rg] += bcol[nt];

    // ---- row sum-of-squares (q and k blocks only) ----
    if (by < 16) {
        float* ssq = (by < 8) ? qssq : kssq;
        #pragma unroll
        for (int mt = 0; mt < 4; ++mt)
            #pragma unroll
            for (int rg = 0; rg < 4; ++rg) {
                float s = acc[mt][0][rg] * acc[mt][0][rg]
                        + acc[mt][1][rg] * acc[mt][1][rg]
                        + acc[mt][2][rg] * acc[mt][2][rg]
                        + acc[mt][3][rg] * acc[mt][3][rg];
                #pragma unroll
                for (int m = 1; m < 16; m <<= 1) s += __shfl_xor(s, m, 16);
                if (l15 == 0)
                    atomicAdd(&ssq[r0 + wm * 64 + mt * 16 + quad * 4 + rg], s);
            }
    }

    // ---- store bf16 ----
    u16* dst;
    int ldc, cb;
    if (by < 8) { dst = qb;  ldc = 1024; cb = c0; }
    else        { dst = kvb; ldc = 2048; cb = c0 - 1024; }
    #pragma unroll
    for (int mt = 0; mt < 4; ++mt)
        #pragma unroll
        for (int nt = 0; nt < 4; ++nt) {
            int col = cb + wn * 64 + nt * 16 + l15;
            #pragma unroll
            for (int rg = 0; rg < 4; ++rg) {
                int row = r0 + wm * 64 + mt * 16 + quad * 4 + rg;
                dst[(size_t)row * ldc + col] = f2bf(acc[mt][nt][rg]);
            }
        }
}

// ---------------- Kernel 3: kv[b,d] = sum_t k*v*rsqrt(kssq) ----------------
__global__ void kv_reduce(const u16* __restrict__ kvb, const float* __restrict__ kssq,
                          float* __restrict__ kv)
{
    int d  = threadIdx.x * 8;                  // 128 threads cover 1024 d
    int b  = blockIdx.y;                       // 0..3
    int t0 = blockIdx.x * 64;                  // 128 t-chunks of 64 rows
    float a[8];
    #pragma unroll
    for (int e = 0; e < 8; ++e) a[e] = 0.0f;
    for (int r = 0; r < 64; ++r) {
        int row = b * T_DIM + t0 + r;
        float kin = rsqrtf(kssq[row]);
        short8 k8 = *reinterpret_cast<const short8*>(kvb + (size_t)row * 2048 + d);
        short8 v8 = *reinterpret_cast<const short8*>(kvb + (size_t)row * 2048 + 1024 + d);
        #pragma unroll
        for (int e = 0; e < 8; ++e)
            a[e] += bf2f((u16)k8[e]) * bf2f((u16)v8[e]) * kin;
    }
    #pragma unroll
    for (int e = 0; e < 8; ++e)
        atomicAdd(&kv[b * D_DIM + d + e], a[e]);
}

// ---------------- Kernel 4: out = q*rsqrt(qssq)*kv*scale + bias (fp32) ----------------
__global__ void finalize(const u16* __restrict__ qb, const float* __restrict__ qssq,
                         const float* __restrict__ kv, const float* __restrict__ scale,
                         const float* __restrict__ bias, float* __restrict__ out)
{
    size_t idx = (size_t)blockIdx.x * 256 + threadIdx.x;   // vec8 index
    int row = (int)(idx >> 7);
    int dv  = ((int)idx & 127) * 8;
    int b   = row >> 13;
    float qi = rsqrtf(qssq[row]);
    short8 qv = *reinterpret_cast<const short8*>(qb + (size_t)row * D_DIM + dv);
    const float* kvp = kv + b * D_DIM + dv;
    const float* sp  = scale + dv;
    const float* bp  = bias + dv;
    float4 o0, o1;
    o0.x = bf2f((u16)qv[0]) * qi * kvp[0] * sp[0] + bp[0];
    o0.y = bf2f((u16)qv[1]) * qi * kvp[1] * sp[1] + bp[1];
    o0.z = bf2f((u16)qv[2]) * qi * kvp[2] * sp[2] + bp[2];
    o0.w = bf2f((u16)qv[3]) * qi * kvp[3] * sp[3] + bp[3];
    o1.x = bf2f((u16)qv[4]) * qi * kvp[4] * sp[4] + bp[4];
    o1.y = bf2f((u16)qv[5]) * qi * kvp[5] * sp[5] + bp[5];
    o1.z = bf2f((u16)qv[6]) * qi * kvp[6] * sp[6] + bp[6];
    o1.w = bf2f((u16)qv[7]) * qi * kvp[7] * sp[7] + bp[7];
    float* op = out + (size_t)row * D_DIM + dv;
    *reinterpret_cast<float4*>(op)     = o0;
    *reinterpret_cast<float4*>(op + 4) = o1;
}

extern "C" void kernel_launch(void* const* d_in, const int* in_sizes, int n_in,
                              void* d_out, int out_size, void* d_ws, size_t ws_size,
                              hipStream_t stream) {
    const float* x     = (const float*)d_in[0];
    const float* W     = (const float*)d_in[1];
    const float* bqkv  = (const float*)d_in[2];
    const float* scale = (const float*)d_in[3];
    const float* bias  = (const float*)d_in[4];
    float* out = (float*)d_out;

    // d_out doubles as scratch until finalize: xb (64 MB) + WT (6 MB) < 128 MB
    u16* xb = (u16*)d_out;
    u16* WT = (u16*)((char*)d_out + 67108864);

    char* ws = (char*)d_ws;
    u16*   qb   = (u16*)ws;                         //  67,108,864 B
    u16*   kvb  = (u16*)(ws + 67108864);            // 134,217,728 B
    float* qssq = (float*)(ws + 201326592);         //     131,072 B
    float* kssq = (float*)(ws + 201457664);         //     131,072 B
    float* kv   = (float*)(ws + 201588736);         //      16,384 B

    convert_x  <<<dim3(ROWS * D_DIM / 8 / 256), dim3(256), 0, stream>>>(x, xb);
    transpose_w<<<dim3(96, 32), dim3(32, 8), 0, stream>>>(W, WT);
    hipMemsetAsync(qssq, 0, 131072 + 131072 + 16384, stream);
    gemm_k     <<<dim3(ROWS / 128, 24), dim3(256), 0, stream>>>(xb, WT, bqkv, qb, kvb, qssq, kssq);
    kv_reduce  <<<dim3(T_DIM / 64, 4), dim3(128), 0, stream>>>(kvb, kssq, kv);
    finalize   <<<dim3(ROWS * (D_DIM / 8) / 256), dim3(256), 0, stream>>>(qb, qssq, kv, scale, bias, out);
}